// Round 7
// baseline (361.837 us; speedup 1.0000x reference)
//
#include <hip/hip_runtime.h>
#include <cmath>

constexpr int S_LEN = 2048;
constexpr float EPS = 1e-8f;

typedef unsigned uvec32 __attribute__((ext_vector_type(32)));

__device__ __forceinline__ float fin(float v) { return isfinite(v) ? v : 0.0f; }

// monotonic float-bits -> orderable uint (operates on raw bits)
__device__ __forceinline__ unsigned f2o_bits(unsigned u) {
    return (u & 0x80000000u) ? ~u : (u | 0x80000000u);
}
__device__ __forceinline__ float o2f(unsigned u) {
    return __uint_as_float((u & 0x80000000u) ? (u ^ 0x80000000u) : ~u);
}

// ---- DPP helpers: ctrl/rmask are ICEs via template params ----
template <int Ctrl, int Rmask>
__device__ __forceinline__ int dpp_zero_i(int x) {
    return __builtin_amdgcn_update_dpp(0, x, Ctrl, Rmask, 0xF, true);
}
template <int Ctrl>
__device__ __forceinline__ int dpp_keep_i(int x) {
    return __builtin_amdgcn_update_dpp(x, x, Ctrl, 0xF, 0xF, false);
}

// full-wave int sum (VALU pipe), uniform result via readlane (-> SGPR)
__device__ __forceinline__ int wred_add_i(int v) {
    v += dpp_zero_i<0xB1, 0xF>(v);   // quad_perm [1,0,3,2]
    v += dpp_zero_i<0x4E, 0xF>(v);   // quad_perm [2,3,0,1]
    v += dpp_zero_i<0x114, 0xF>(v);  // row_shr:4
    v += dpp_zero_i<0x118, 0xF>(v);  // row_shr:8
    v += dpp_zero_i<0x142, 0xA>(v);  // row_bcast:15 -> rows 1,3
    v += dpp_zero_i<0x143, 0xC>(v);  // row_bcast:31 -> rows 2,3
    return __builtin_amdgcn_readlane(v, 63);
}
__device__ __forceinline__ float wred_add_f(float v) {
    #define ADDF(CT, RM) v += __uint_as_float((unsigned)dpp_zero_i<CT, RM>((int)__float_as_uint(v)))
    ADDF(0xB1, 0xF); ADDF(0x4E, 0xF); ADDF(0x114, 0xF);
    ADDF(0x118, 0xF); ADDF(0x142, 0xA); ADDF(0x143, 0xC);
    #undef ADDF
    return __uint_as_float((unsigned)__builtin_amdgcn_readlane((int)__float_as_uint(v), 63));
}
__device__ __forceinline__ float wred_min_f(float v) {
    #define MINF(CT) v = fminf(v, __uint_as_float((unsigned)dpp_keep_i<CT>((int)__float_as_uint(v))))
    MINF(0xB1); MINF(0x4E); MINF(0x114); MINF(0x118); MINF(0x142); MINF(0x143);
    #undef MINF
    return __uint_as_float((unsigned)__builtin_amdgcn_readlane((int)__float_as_uint(v), 63));
}
__device__ __forceinline__ float wred_max_f(float v) {
    #define MAXF(CT) v = fmaxf(v, __uint_as_float((unsigned)dpp_keep_i<CT>((int)__float_as_uint(v))))
    MAXF(0xB1); MAXF(0x4E); MAXF(0x114); MAXF(0x118); MAXF(0x142); MAXF(0x143);
    #undef MAXF
    return __uint_as_float((unsigned)__builtin_amdgcn_readlane((int)__float_as_uint(v), 63));
}
__device__ __forceinline__ unsigned wred_umin(unsigned v) {
    #define MINU(CT) { unsigned t = (unsigned)dpp_keep_i<CT>((int)v); v = v < t ? v : t; }
    MINU(0xB1) MINU(0x4E) MINU(0x114) MINU(0x118) MINU(0x142) MINU(0x143)
    #undef MINU
    return (unsigned)__builtin_amdgcn_readlane((int)v, 63);
}
__device__ __forceinline__ float readlane_f(float x, int l) {
    return __uint_as_float((unsigned)__builtin_amdgcn_readlane((int)__float_as_uint(x), l));
}

// Hacker's Delight 32x32 bit transpose (anti-diagonal; involution).
__device__ __forceinline__ void transpose32(uvec32& A) {
    #pragma unroll
    for (int j = 16; j; j >>= 1) {
        unsigned m = (j == 16) ? 0x0000FFFFu : (j == 8) ? 0x00FF00FFu
                   : (j == 4) ? 0x0F0F0F0Fu : (j == 2) ? 0x33333333u : 0x55555555u;
        #pragma unroll
        for (int k = 0; k < 32; k++) {
            if (!(k & j)) {
                unsigned t = (A[k] ^ (A[k | j] >> j)) & m;
                A[k] = A[k] ^ t;
                A[k | j] = A[k | j] ^ (t << j);
            }
        }
    }
}

#define VF(e) __uint_as_float(a[e])

// ============ K1: streaming stats (wave per row, zero LDS) ============
__global__ __launch_bounds__(256) void stats_kernel(
    const float* __restrict__ x, float* __restrict__ feats, int nrows)
{
    const int gw   = (blockIdx.x * 256 + threadIdx.x) >> 6;  // global wave id = row
    const int lane = threadIdx.x & 63;
    if (gw >= nrows) return;

    uvec32 a;
    const float* xr = x + (size_t)gw * S_LEN + lane * 32;
    #pragma unroll
    for (int q = 0; q < 8; q++) {
        float4 t = reinterpret_cast<const float4*>(xr)[q];
        a[4 * q + 0] = __float_as_uint(t.x); a[4 * q + 1] = __float_as_uint(t.y);
        a[4 * q + 2] = __float_as_uint(t.z); a[4 * q + 3] = __float_as_uint(t.w);
    }

    // phase A accumulators
    float s1 = 0.f, s2 = 0.f, sd2 = 0.f, sad = 0.f;
    float p1 = 0.f, p7 = 0.f, p24 = 0.f, se1 = 0.f, se2 = 0.f;
    float mn = VF(0), mx = VF(0);
    #pragma unroll
    for (int e = 0; e < 32; e++) {
        float val = VF(e);
        s1 += val; s2 = fmaf(val, val, s2);
        mn = fminf(mn, val); mx = fmaxf(mx, val);
    }
    #pragma unroll
    for (int e = 0; e < 31; e++) {
        float d = VF(e + 1) - VF(e);
        sd2 = fmaf(d, d, sd2); sad += fabsf(d);
        p1 = fmaf(VF(e), VF(e + 1), p1);
    }
    #pragma unroll
    for (int e = 0; e < 25; e++) p7 = fmaf(VF(e), VF(e + 7), p7);
    #pragma unroll
    for (int e = 0; e < 8; e++)  p24 = fmaf(VF(e), VF(e + 24), p24);

    const bool notlast = (lane < 63);
    #pragma unroll
    for (int j = 0; j < 24; j++) {
        float nb = __shfl_down(VF(j), 1, 64);
        float g = notlast ? nb : 0.f;
        p24 = fmaf(VF(8 + j), g, p24);
        if (j < 7) p7 = fmaf(VF(25 + j), g, p7);
        if (j == 0 && notlast) {
            float d = nb - VF(31);
            sd2 = fmaf(d, d, sd2); sad += fabsf(d);
            p1 = fmaf(VF(31), nb, p1);
        }
    }
    // seasonal x[::24]: i = 32*lane + e == 0 (mod 24)
    {
        int r3 = lane % 3;
        float sv = (r3 == 0) ? VF(0) : ((r3 == 1) ? VF(16) : VF(8));
        se1 += sv; se2 = fmaf(sv, sv, se2);
        if (r3 == 0) { se1 += VF(24); se2 = fmaf(VF(24), VF(24), se2); }
    }

    // head/tail partials: computed on all lanes, landed in SGPRs immediately
    float aa = 0, bb = 0, h7v = 0, hq7v = 0;
    #pragma unroll
    for (int e = 0; e < 24; e++) {
        aa += VF(e); bb = fmaf(VF(e), VF(e), bb);
        if (e == 6) { h7v = aa; hq7v = bb; }
    }
    float cc = 0, dd = 0, t7v = 0, tq7v = 0;
    #pragma unroll
    for (int e = 31; e >= 8; e--) {
        cc += VF(e); dd = fmaf(VF(e), VF(e), dd);
        if (e == 25) { t7v = cc; tq7v = dd; }
    }
    const float h1  = readlane_f(VF(0), 0),   t1  = readlane_f(VF(31), 63);
    const float h7  = readlane_f(h7v, 0),     hq7 = readlane_f(hq7v, 0);
    const float h24 = readlane_f(aa, 0),      hq24 = readlane_f(bb, 0);
    const float t7  = readlane_f(t7v, 63),    tq7 = readlane_f(tq7v, 63);
    const float t24 = readlane_f(cc, 63),     tq24 = readlane_f(dd, 63);
    const float hq1 = h1 * h1, tq1 = t1 * t1;

    // wave reductions -> SGPR-uniform
    float S1  = wred_add_f(s1);
    float mean = S1 * (1.0f / S_LEN);
    float S2  = wred_add_f(s2);
    float SD2 = wred_add_f(sd2);
    float SAD = wred_add_f(sad);
    float P1  = wred_add_f(p1);
    float P7  = wred_add_f(p7);
    float P24 = wred_add_f(p24);
    float SE1 = wred_add_f(se1);
    float SE2 = wred_add_f(se2);
    float MN  = wred_min_f(mn);
    float MX  = wred_max_f(mx);

    // central moments (two-pass)
    float c2 = 0.f, c3 = 0.f, c4 = 0.f;
    #pragma unroll
    for (int e = 0; e < 32; e++) {
        float xc = VF(e) - mean;
        float q = xc * xc;
        c2 += q; c3 = fmaf(q, xc, c3); c4 = fmaf(q, q, c4);
    }
    float C2 = wred_add_f(c2), C3 = wred_add_f(c3), C4 = wred_add_f(c4);

    const float Sf = (float)S_LEN;
    const float nd = Sf - 1.0f;
    float m2v = C2 / Sf, m3v = C3 / Sf, m4v = C4 / Sf;
    float stdv = sqrtf(m2v);
    float dmean = (t1 - h1) / nd;
    float dvar = SD2 / nd - dmean * dmean;
    float std_diff = sqrtf(fmaxf(dvar, 0.f));
    float trend = std_diff / (stdv + EPS);

    float ac[3];
    {
        const float Ls[3] = {1.f, 7.f, 24.f};
        const float Ps[3] = {P1, P7, P24};
        const float hd[3] = {h1, h7, h24},   hqv[3] = {hq1, hq7, hq24};
        const float tl[3] = {t1, t7, t24},   tqv[3] = {tq1, tq7, tq24};
        #pragma unroll
        for (int q = 0; q < 3; q++) {
            float n = Sf - Ls[q];
            float sa = S1 - tl[q], sb = S1 - hd[q];
            float qa = S2 - tqv[q], qb = S2 - hqv[q];
            float am = sa / n, bm = sb / n;
            float cov = Ps[q] / n - am * bm;
            float as_ = sqrtf(fmaxf(qa / n - am * am, 0.f));
            float bs_ = sqrtf(fmaxf(qb / n - bm * bm, 0.f));
            ac[q] = cov / (as_ * bs_);
        }
    }
    float cv = stdv / (fabsf(mean) + EPS);
    float sm = SE1 / 86.f;
    float svar = SE2 / 86.f - sm * sm;
    float seasonal = svar / (m2v + EPS);
    float skew = m3v / (m2v * stdv);
    float kurt = m4v / (m2v * m2v) - 3.f;

    if (lane == 0) {
        float* fp = feats + (size_t)gw * 20;
        fp[0] = fin(mean);      fp[1] = fin(stdv);
        fp[2] = fin(MN);        fp[3] = fin(MX);
        fp[5] = fin(trend);
        fp[6] = fin(ac[0]);     fp[7] = fin(ac[1]);
        fp[8] = fin(ac[2]);     fp[9] = fin(cv);
        fp[11] = fin(seasonal);
        fp[12] = fin(skew);     fp[13] = fin(kurt);
        fp[14] = Sf;            fp[15] = fin(SAD);
        fp[16] = fin(SAD / nd); fp[17] = fin(std_diff);
    }
}

// ============ K2: percentiles via bit-plane radix select ============
__global__ __launch_bounds__(256) void pct_kernel(
    const float* __restrict__ x, float* __restrict__ feats, int nrows)
{
    const int gw   = (blockIdx.x * 256 + threadIdx.x) >> 6;
    const int lane = threadIdx.x & 63;
    if (gw >= nrows) return;

    uvec32 a;
    const float* xr = x + (size_t)gw * S_LEN + lane * 32;
    #pragma unroll
    for (int q = 0; q < 8; q++) {
        float4 t = reinterpret_cast<const float4*>(xr)[q];
        a[4 * q + 0] = __float_as_uint(t.x); a[4 * q + 1] = __float_as_uint(t.y);
        a[4 * q + 2] = __float_as_uint(t.z); a[4 * q + 3] = __float_as_uint(t.w);
    }
    #pragma unroll
    for (int e = 0; e < 32; e++) a[e] = f2o_bits(a[e]);
    transpose32(a);

    unsigned act0 = ~0u, act1 = ~0u, act2 = ~0u;
    int K0 = 511, K1 = 1023, K2 = 1535;
    unsigned uK0 = 0, uK1 = 0, uK2 = 0;
    #pragma unroll
    for (int b = 31; b >= 0; b--) {
        unsigned mb = a[31 - b];
        unsigned z0 = act0 & ~mb, z1 = act1 & ~mb, z2 = act2 & ~mb;
        int C01 = wred_add_i(__popc(z0) | (__popc(z1) << 16));
        int Cc2 = wred_add_i(__popc(z2));
        int c0 = C01 & 0xFFFF;
        int c1 = (int)((unsigned)C01 >> 16);
        if (K0 < c0)  act0 = z0; else { K0 -= c0;  act0 &= mb; uK0 |= (1u << b); }
        if (K1 < c1)  act1 = z1; else { K1 -= c1;  act1 &= mb; uK1 |= (1u << b); }
        if (K2 < Cc2) act2 = z2; else { K2 -= Cc2; act2 &= mb; uK2 |= (1u << b); }
    }
    int e01 = wred_add_i(__popc(act0) | (__popc(act1) << 16));
    int eq0 = e01 & 0xFFFF, eq1 = (int)((unsigned)e01 >> 16);
    int eq2 = wred_add_i(__popc(act2));

    transpose32(a);  // involution -> recover orderable values
    unsigned m0 = ~0u, m1 = ~0u, m2 = ~0u;
    #pragma unroll
    for (int e = 0; e < 32; e++) {
        unsigned ue = a[e];
        if (ue > uK0) m0 = m0 < ue ? m0 : ue;
        if (ue > uK1) m1 = m1 < ue ? m1 : ue;
        if (ue > uK2) m2 = m2 < ue ? m2 : ue;
    }
    m0 = wred_umin(m0); m1 = wred_umin(m1); m2 = wred_umin(m2);

    float v511 = o2f(uK0), v1023 = o2f(uK1), v1535 = o2f(uK2);
    float v512  = (K0 + 1 < eq0) ? v511  : o2f(m0);
    float v1024 = (K1 + 1 < eq1) ? v1023 : o2f(m1);
    float v1536 = (K2 + 1 < eq2) ? v1535 : o2f(m2);
    float p25 = v511 + 0.75f * (v512 - v511);
    float med = 0.5f * (v1023 + v1024);
    float p75 = v1535 + 0.25f * (v1536 - v1535);
    float iqr = p75 - p25;

    if (lane == 0) {
        float* fp = feats + (size_t)gw * 20;
        fp[4]  = fin(med);
        fp[10] = fin(iqr);
        fp[18] = fin(p25);
        fp[19] = fin(p75);
    }
}

// ============ K3: tiny MLP (wave per row, zero LDS) ============
__global__ __launch_bounds__(256) void mlp_kernel(
    const float* __restrict__ feats,
    const float* __restrict__ W1, const float* __restrict__ b1,
    const float* __restrict__ W2, const float* __restrict__ b2,
    float* __restrict__ out, int nrows)
{
    const int gw   = (blockIdx.x * 256 + threadIdx.x) >> 6;
    const int lane = threadIdx.x & 63;
    if (gw >= nrows) return;

    const float* fp = feats + (size_t)gw * 20;
    float h = b1[lane];
    #pragma unroll
    for (int j = 0; j < 20; j++) h = fmaf(fp[j], W1[lane * 20 + j], h);
    h = fmaxf(h, 0.f);

    float o0 = b2[lane], o1 = b2[lane + 64];
    #pragma unroll
    for (int k = 0; k < 64; k++) {
        float hk = readlane_f(h, k);          // constant lane -> scalar broadcast
        o0 = fmaf(hk, W2[lane * 64 + k], o0);         // W2 row `lane`    (L1-resident)
        o1 = fmaf(hk, W2[(lane + 64) * 64 + k], o1);  // W2 row `lane+64`
    }
    out[(size_t)gw * 128 + lane]      = o0;
    out[(size_t)gw * 128 + 64 + lane] = o1;
}

extern "C" void kernel_launch(void* const* d_in, const int* in_sizes, int n_in,
                              void* d_out, int out_size, void* d_ws, size_t ws_size,
                              hipStream_t stream) {
    const float* x  = (const float*)d_in[0];
    const float* W1 = (const float*)d_in[1];
    const float* b1 = (const float*)d_in[2];
    const float* W2 = (const float*)d_in[3];
    const float* b2 = (const float*)d_in[4];
    float* out   = (float*)d_out;
    float* feats = (float*)d_ws;     // nrows*20 floats = 1.31 MB scratch
    int nrows = in_sizes[0] / S_LEN;
    int blocks = (nrows + 3) / 4;    // 4 waves (rows) per 256-thread block
    stats_kernel<<<blocks, 256, 0, stream>>>(x, feats, nrows);
    pct_kernel<<<blocks, 256, 0, stream>>>(x, feats, nrows);
    mlp_kernel<<<blocks, 256, 0, stream>>>(feats, W1, b1, W2, b2, out, nrows);
}

// Round 8
// 283.798 us; speedup vs baseline: 1.2750x; 1.2750x over previous
//
#include <hip/hip_runtime.h>
#include <cmath>

constexpr int S_LEN = 2048;
constexpr float EPS = 1e-8f;

typedef unsigned uvec32 __attribute__((ext_vector_type(32)));

__device__ __forceinline__ float fin(float v) { return isfinite(v) ? v : 0.0f; }

__device__ __forceinline__ unsigned f2o_bits(unsigned u) {
    return (u & 0x80000000u) ? ~u : (u | 0x80000000u);
}
__device__ __forceinline__ float o2f(unsigned u) {
    return __uint_as_float((u & 0x80000000u) ? (u ^ 0x80000000u) : ~u);
}

// ---- DPP helpers (ctrl/rmask are ICEs via template params) ----
template <int Ctrl, int Rmask>
__device__ __forceinline__ int dpp_zero_i(int x) {
    return __builtin_amdgcn_update_dpp(0, x, Ctrl, Rmask, 0xF, true);
}
template <int Ctrl>
__device__ __forceinline__ int dpp_keep_i(int x) {
    return __builtin_amdgcn_update_dpp(x, x, Ctrl, 0xF, 0xF, false);
}
__device__ __forceinline__ int wred_add_i(int v) {
    v += dpp_zero_i<0xB1, 0xF>(v);
    v += dpp_zero_i<0x4E, 0xF>(v);
    v += dpp_zero_i<0x114, 0xF>(v);
    v += dpp_zero_i<0x118, 0xF>(v);
    v += dpp_zero_i<0x142, 0xA>(v);
    v += dpp_zero_i<0x143, 0xC>(v);
    return __builtin_amdgcn_readlane(v, 63);
}
__device__ __forceinline__ float wred_add_f(float v) {
    #define ADDF(CT, RM) v += __uint_as_float((unsigned)dpp_zero_i<CT, RM>((int)__float_as_uint(v)))
    ADDF(0xB1, 0xF); ADDF(0x4E, 0xF); ADDF(0x114, 0xF);
    ADDF(0x118, 0xF); ADDF(0x142, 0xA); ADDF(0x143, 0xC);
    #undef ADDF
    return __uint_as_float((unsigned)__builtin_amdgcn_readlane((int)__float_as_uint(v), 63));
}
__device__ __forceinline__ float wred_min_f(float v) {
    #define MINF(CT) v = fminf(v, __uint_as_float((unsigned)dpp_keep_i<CT>((int)__float_as_uint(v))))
    MINF(0xB1); MINF(0x4E); MINF(0x114); MINF(0x118); MINF(0x142); MINF(0x143);
    #undef MINF
    return __uint_as_float((unsigned)__builtin_amdgcn_readlane((int)__float_as_uint(v), 63));
}
__device__ __forceinline__ float wred_max_f(float v) {
    #define MAXF(CT) v = fmaxf(v, __uint_as_float((unsigned)dpp_keep_i<CT>((int)__float_as_uint(v))))
    MAXF(0xB1); MAXF(0x4E); MAXF(0x114); MAXF(0x118); MAXF(0x142); MAXF(0x143);
    #undef MAXF
    return __uint_as_float((unsigned)__builtin_amdgcn_readlane((int)__float_as_uint(v), 63));
}
__device__ __forceinline__ unsigned wred_umin(unsigned v) {
    #define MINU(CT) { unsigned t = (unsigned)dpp_keep_i<CT>((int)v); v = v < t ? v : t; }
    MINU(0xB1) MINU(0x4E) MINU(0x114) MINU(0x118) MINU(0x142) MINU(0x143)
    #undef MINU
    return (unsigned)__builtin_amdgcn_readlane((int)v, 63);
}
__device__ __forceinline__ float readlane_f(float x, int l) {
    return __uint_as_float((unsigned)__builtin_amdgcn_readlane((int)__float_as_uint(x), l));
}

// Hacker's Delight 32x32 bit transpose (anti-diagonal; involution).
__device__ __forceinline__ void transpose32(uvec32& A) {
    #pragma unroll
    for (int j = 16; j; j >>= 1) {
        unsigned m = (j == 16) ? 0x0000FFFFu : (j == 8) ? 0x00FF00FFu
                   : (j == 4) ? 0x0F0F0F0Fu : (j == 2) ? 0x33333333u : 0x55555555u;
        #pragma unroll
        for (int k = 0; k < 32; k++) {
            if (!(k & j)) {
                unsigned t = (A[k] ^ (A[k | j] >> j)) & m;
                A[k] = A[k] ^ t;
                A[k | j] = A[k | j] ^ (t << j);
            }
        }
    }
}

#define VF(e) __uint_as_float(a[e])

// feats layout in d_ws (slot -> original feature):
// 0..15: mean,std,min,max,trend,ac1,ac7,ac24,cv,seasonal,skew,kurt,len,sad,madiff,stddiff
// 16..19: median,iqr,p25,p75
// MLP stages W1 with matching column permutation.

// ============ K1: stats + percentiles fused (wave/row, zero LDS) ============
__global__ __launch_bounds__(256) void statspct_kernel(
    const float* __restrict__ x, float* __restrict__ feats, int nrows)
{
    const int gw   = (blockIdx.x * 256 + threadIdx.x) >> 6;  // row
    const int lane = threadIdx.x & 63;
    if (gw >= nrows) return;

    uvec32 a;
    const float* xr = x + (size_t)gw * S_LEN + lane * 32;
    #pragma unroll
    for (int q = 0; q < 8; q++) {
        float4 t = reinterpret_cast<const float4*>(xr)[q];
        a[4 * q + 0] = __float_as_uint(t.x); a[4 * q + 1] = __float_as_uint(t.y);
        a[4 * q + 2] = __float_as_uint(t.z); a[4 * q + 3] = __float_as_uint(t.w);
    }

    // ---------------- phase 1: streaming stats ----------------
    float s1 = 0.f, s2 = 0.f, sd2 = 0.f, sad = 0.f;
    float p1 = 0.f, p7 = 0.f, p24 = 0.f, se1 = 0.f, se2 = 0.f;
    float mn = VF(0), mx = VF(0);
    #pragma unroll
    for (int e = 0; e < 32; e++) {
        float val = VF(e);
        s1 += val; s2 = fmaf(val, val, s2);
        mn = fminf(mn, val); mx = fmaxf(mx, val);
    }
    #pragma unroll
    for (int e = 0; e < 31; e++) {
        float d = VF(e + 1) - VF(e);
        sd2 = fmaf(d, d, sd2); sad += fabsf(d);
        p1 = fmaf(VF(e), VF(e + 1), p1);
    }
    #pragma unroll
    for (int e = 0; e < 25; e++) p7 = fmaf(VF(e), VF(e + 7), p7);
    #pragma unroll
    for (int e = 0; e < 8; e++)  p24 = fmaf(VF(e), VF(e + 24), p24);

    const bool notlast = (lane < 63);
    #pragma unroll
    for (int j = 0; j < 24; j++) {
        float nb = __shfl_down(VF(j), 1, 64);
        float g = notlast ? nb : 0.f;
        p24 = fmaf(VF(8 + j), g, p24);
        if (j < 7) p7 = fmaf(VF(25 + j), g, p7);
        if (j == 0 && notlast) {
            float d = nb - VF(31);
            sd2 = fmaf(d, d, sd2); sad += fabsf(d);
            p1 = fmaf(VF(31), nb, p1);
        }
    }
    {   // seasonal x[::24]
        int r3 = lane % 3;
        float sv = (r3 == 0) ? VF(0) : ((r3 == 1) ? VF(16) : VF(8));
        se1 += sv; se2 = fmaf(sv, sv, se2);
        if (r3 == 0) { se1 += VF(24); se2 = fmaf(VF(24), VF(24), se2); }
    }
    // head/tail partials -> SGPRs
    float aa = 0, bb = 0, h7v = 0, hq7v = 0;
    #pragma unroll
    for (int e = 0; e < 24; e++) {
        aa += VF(e); bb = fmaf(VF(e), VF(e), bb);
        if (e == 6) { h7v = aa; hq7v = bb; }
    }
    float cc = 0, dd = 0, t7v = 0, tq7v = 0;
    #pragma unroll
    for (int e = 31; e >= 8; e--) {
        cc += VF(e); dd = fmaf(VF(e), VF(e), dd);
        if (e == 25) { t7v = cc; tq7v = dd; }
    }
    const float h1  = readlane_f(VF(0), 0),   t1  = readlane_f(VF(31), 63);
    const float h7  = readlane_f(h7v, 0),     hq7 = readlane_f(hq7v, 0);
    const float h24 = readlane_f(aa, 0),      hq24 = readlane_f(bb, 0);
    const float t7  = readlane_f(t7v, 63),    tq7 = readlane_f(tq7v, 63);
    const float t24 = readlane_f(cc, 63),     tq24 = readlane_f(dd, 63);
    const float hq1 = h1 * h1, tq1 = t1 * t1;

    float S1  = wred_add_f(s1);
    float mean = S1 * (1.0f / S_LEN);
    float S2  = wred_add_f(s2);
    float SD2 = wred_add_f(sd2);
    float SAD = wred_add_f(sad);
    float P1  = wred_add_f(p1);
    float P7  = wred_add_f(p7);
    float P24 = wred_add_f(p24);
    float SE1 = wred_add_f(se1);
    float SE2 = wred_add_f(se2);
    float MN  = wred_min_f(mn);
    float MX  = wred_max_f(mx);

    float c2 = 0.f, c3 = 0.f, c4 = 0.f;
    #pragma unroll
    for (int e = 0; e < 32; e++) {
        float xc = VF(e) - mean;
        float q = xc * xc;
        c2 += q; c3 = fmaf(q, xc, c3); c4 = fmaf(q, q, c4);
    }
    float C2 = wred_add_f(c2), C3 = wred_add_f(c3), C4 = wred_add_f(c4);

    // 16 stat features -> global NOW (frees registers across the select)
    {
        const float Sf = (float)S_LEN;
        const float nd = Sf - 1.0f;
        float m2v = C2 / Sf, m3v = C3 / Sf, m4v = C4 / Sf;
        float stdv = sqrtf(m2v);
        float dmean = (t1 - h1) / nd;
        float dvar = SD2 / nd - dmean * dmean;
        float std_diff = sqrtf(fmaxf(dvar, 0.f));
        float trend = std_diff / (stdv + EPS);
        float ac[3];
        const float Ls[3] = {1.f, 7.f, 24.f};
        const float Ps[3] = {P1, P7, P24};
        const float hd[3] = {h1, h7, h24},   hqv[3] = {hq1, hq7, hq24};
        const float tl[3] = {t1, t7, t24},   tqv[3] = {tq1, tq7, tq24};
        #pragma unroll
        for (int q = 0; q < 3; q++) {
            float n = Sf - Ls[q];
            float sa = S1 - tl[q], sb = S1 - hd[q];
            float qa = S2 - tqv[q], qb = S2 - hqv[q];
            float am = sa / n, bm = sb / n;
            float cov = Ps[q] / n - am * bm;
            float as_ = sqrtf(fmaxf(qa / n - am * am, 0.f));
            float bs_ = sqrtf(fmaxf(qb / n - bm * bm, 0.f));
            ac[q] = cov / (as_ * bs_);
        }
        float cv = stdv / (fabsf(mean) + EPS);
        float sm = SE1 / 86.f;
        float svar = SE2 / 86.f - sm * sm;
        float seasonal = svar / (m2v + EPS);
        float skew = m3v / (m2v * stdv);
        float kurt = m4v / (m2v * m2v) - 3.f;
        if (lane == 0) {
            float4* fp = (float4*)(feats + (size_t)gw * 20);
            fp[0] = make_float4(fin(mean), fin(stdv), fin(MN), fin(MX));
            fp[1] = make_float4(fin(trend), fin(ac[0]), fin(ac[1]), fin(ac[2]));
            fp[2] = make_float4(fin(cv), fin(seasonal), fin(skew), fin(kurt));
            fp[3] = make_float4(Sf, fin(SAD), fin(SAD / nd), fin(std_diff));
        }
    }

    // ---------------- phase 2: bit-plane radix select ----------------
    #pragma unroll
    for (int e = 0; e < 32; e++) a[e] = f2o_bits(a[e]);
    transpose32(a);

    unsigned act0 = ~0u, act1 = ~0u, act2 = ~0u;
    int K0 = 511, K1 = 1023, K2 = 1535;
    unsigned uK0 = 0, uK1 = 0, uK2 = 0;
    #pragma unroll
    for (int b = 31; b >= 0; b--) {
        unsigned mb = a[31 - b];
        unsigned nmb = ~mb;
        unsigned z0 = act0 & nmb, z1 = act1 & nmb, z2 = act2 & nmb;
        int C01 = wred_add_i(__popc(z0) | (__popc(z1) << 16));
        int Cc2 = wred_add_i(__popc(z2));
        int c0 = C01 & 0xFFFF;
        int c1 = (int)((unsigned)C01 >> 16);
        if (K0 < c0)  act0 = z0; else { K0 -= c0;  act0 &= mb; uK0 |= (1u << b); }
        if (K1 < c1)  act1 = z1; else { K1 -= c1;  act1 &= mb; uK1 |= (1u << b); }
        if (K2 < Cc2) act2 = z2; else { K2 -= Cc2; act2 &= mb; uK2 |= (1u << b); }
    }
    int e01 = wred_add_i(__popc(act0) | (__popc(act1) << 16));
    int eq0 = e01 & 0xFFFF, eq1 = (int)((unsigned)e01 >> 16);
    int eq2 = wred_add_i(__popc(act2));

    transpose32(a);  // involution -> recover orderable values
    unsigned m0 = ~0u, m1 = ~0u, m2 = ~0u;
    #pragma unroll
    for (int e = 0; e < 32; e++) {
        unsigned ue = a[e];
        if (ue > uK0) m0 = m0 < ue ? m0 : ue;
        if (ue > uK1) m1 = m1 < ue ? m1 : ue;
        if (ue > uK2) m2 = m2 < ue ? m2 : ue;
    }
    m0 = wred_umin(m0); m1 = wred_umin(m1); m2 = wred_umin(m2);

    float v511 = o2f(uK0), v1023 = o2f(uK1), v1535 = o2f(uK2);
    float v512  = (K0 + 1 < eq0) ? v511  : o2f(m0);
    float v1024 = (K1 + 1 < eq1) ? v1023 : o2f(m1);
    float v1536 = (K2 + 1 < eq2) ? v1535 : o2f(m2);
    float p25 = v511 + 0.75f * (v512 - v511);
    float med = 0.5f * (v1023 + v1024);
    float p75 = v1535 + 0.25f * (v1536 - v1535);
    float iqr = p75 - p25;

    if (lane == 0) {
        float4* fp = (float4*)(feats + (size_t)gw * 20);
        fp[4] = make_float4(fin(med), fin(iqr), fin(p25), fin(p75));
    }
}

// ============ K2: MLP with LDS-staged (permuted) weights ============
__global__ __launch_bounds__(256) void mlp_kernel(
    const float* __restrict__ feats,
    const float* __restrict__ W1, const float* __restrict__ b1,
    const float* __restrict__ W2, const float* __restrict__ b2,
    float* __restrict__ out, int nrows)
{
    __shared__ float w2s[128 * 65];   // +65 pad -> (j+k)%32 banks, 2-way = free
    __shared__ float w1s[64 * 21];
    __shared__ float hs[4 * 64];

    static const int perm[20] = {0,1,2,3,5,6,7,8,9,11,12,13,14,15,16,17,4,10,18,19};

    const int tid  = threadIdx.x;
    const int lane = tid & 63;
    const int w    = tid >> 6;

    for (int n = tid; n < 64 * 20; n += 256)
        w1s[(n / 20) * 21 + (n % 20)] = W1[(n / 20) * 20 + perm[n % 20]];
    #pragma unroll 8
    for (int it = 0; it < 32; it++) {
        int n = tid + 256 * it;
        w2s[(n >> 6) * 65 + (n & 63)] = W2[n];
    }
    const float b1v = b1[lane];
    const int j  = tid & 127;
    const int r0 = tid >> 7;
    const float b2v = b2[j];
    __syncthreads();

    for (int rg = blockIdx.x * 4; rg < nrows; rg += gridDim.x * 4) {
        // h = relu(feats @ W1p^T + b1): one wave per row
        {
            int row = min(rg + w, nrows - 1);
            const float* fp = feats + (size_t)row * 20;
            float acc = b1v;
            #pragma unroll
            for (int k = 0; k < 20; k++)
                acc = fmaf(fp[k], w1s[lane * 21 + k], acc);
            hs[w * 64 + lane] = fmaxf(acc, 0.f);
        }
        __syncthreads();
        // out = h @ W2^T + b2: thread -> (j, rows r0 & r0+2)
        {
            int r1 = r0 + 2;
            float acc0 = b2v, acc1 = b2v;
            #pragma unroll
            for (int k = 0; k < 64; k++) {
                float wv2 = w2s[j * 65 + k];
                acc0 = fmaf(hs[r0 * 64 + k], wv2, acc0);
                acc1 = fmaf(hs[r1 * 64 + k], wv2, acc1);
            }
            if (rg + r0 < nrows) out[(size_t)(rg + r0) * 128 + j] = acc0;
            if (rg + r1 < nrows) out[(size_t)(rg + r1) * 128 + j] = acc1;
        }
        __syncthreads();
    }
}

extern "C" void kernel_launch(void* const* d_in, const int* in_sizes, int n_in,
                              void* d_out, int out_size, void* d_ws, size_t ws_size,
                              hipStream_t stream) {
    const float* x  = (const float*)d_in[0];
    const float* W1 = (const float*)d_in[1];
    const float* b1 = (const float*)d_in[2];
    const float* W2 = (const float*)d_in[3];
    const float* b2 = (const float*)d_in[4];
    float* out   = (float*)d_out;
    float* feats = (float*)d_ws;     // nrows*20 floats = 1.31 MB scratch
    int nrows = in_sizes[0] / S_LEN;
    int blocks = (nrows + 3) / 4;    // wave per row
    statspct_kernel<<<blocks, 256, 0, stream>>>(x, feats, nrows);
    mlp_kernel<<<512, 256, 0, stream>>>(feats, W1, b1, W2, b2, out, nrows);
}